// Round 11
// baseline (356.694 us; speedup 1.0000x reference)
//
#include <hip/hip_runtime.h>

#define NN   50000
#define INC  128
#define HIDC 256
#define OUTC 128
#define NE   800000
#define MP   50048   // NN padded to 128
#define CAP  64      // CSR capacity per node (P(deg>64) ~ 1e-22)

#define EPB 4096                            // edges per chunk-block
#define NCH ((NE + EPB - 1) / EPB)          // 196 chunks
#define RSZ 6250                            // nodes per dst-range (50000/8)

typedef short bfrag __attribute__((ext_vector_type(8)));   // 8 bf16 = 4 VGPRs
typedef float f32x4 __attribute__((ext_vector_type(4)));
typedef unsigned short us8 __attribute__((ext_vector_type(8)));

__device__ inline unsigned short f2b(float f) {
    union { float f; unsigned u; } v; v.f = f;
    unsigned u = v.u;
    return (unsigned short)((u + 0x7fffu + ((u >> 16) & 1u)) >> 16);
}
__device__ inline float b2f(unsigned short s) {
    union { unsigned u; float f; } v; v.u = ((unsigned)s) << 16;
    return v.f;
}

// ---- fused prep: zero cnt | cast x -> frag A1f x-half | W1 -> B1f | W2 -> B2f ----
__global__ __launch_bounds__(256) void k_prep(
    const float* __restrict__ x, const float* __restrict__ W1l,
    const float* __restrict__ W1r, const float* __restrict__ W2l,
    const float* __restrict__ W2r, unsigned short* __restrict__ A1f,
    unsigned short* __restrict__ B1f, unsigned short* __restrict__ B2f,
    int* __restrict__ cnt) {
    const int b = blockIdx.x;
    if (b < 3125) {
        int t = b * 256 + threadIdx.x;          // < NN*16 = 800000
        int i = t >> 4;
        int c8 = t & 15;
        const float* src = x + (size_t)i * INC + c8 * 8;
        float4 v0 = *(const float4*)src;
        float4 v1 = *(const float4*)(src + 4);
        us8 o = { f2b(v0.x), f2b(v0.y), f2b(v0.z), f2b(v0.w),
                  f2b(v1.x), f2b(v1.y), f2b(v1.z), f2b(v1.w) };
        size_t off = (size_t)(i >> 4) * 4096 + (size_t)(4 + (c8 >> 2)) * 512
                   + (size_t)(c8 & 3) * 128 + (size_t)(i & 15) * 8;
        *(us8*)(A1f + off) = o;
    } else if (b < 3157) {
        int t = (b - 3125) * 256 + threadIdx.x; // < 8192
        int n = t >> 5;
        int k8 = t & 31;
        int k = k8 * 8;
        const float* src = (k < 128) ? (W1l + (size_t)n * INC + k)
                                     : (W1r + (size_t)n * INC + (k - 128));
        float4 v0 = *(const float4*)src;
        float4 v1 = *(const float4*)(src + 4);
        us8 o = { f2b(v0.x), f2b(v0.y), f2b(v0.z), f2b(v0.w),
                  f2b(v1.x), f2b(v1.y), f2b(v1.z), f2b(v1.w) };
        size_t off = (size_t)(n >> 4) * 4096 + (size_t)(k8 >> 2) * 512
                   + (size_t)(k8 & 3) * 128 + (size_t)(n & 15) * 8;
        *(us8*)(B1f + off) = o;
    } else if (b < 3189) {
        int t = (b - 3157) * 256 + threadIdx.x; // < 8192
        int n = t >> 5;
        int k8 = t & 31;
        const float* src = (n < 128) ? (W2l + (size_t)n * HIDC + k8 * 8)
                                     : (W2r + (size_t)(n - 128) * HIDC + k8 * 8);
        float4 v0 = *(const float4*)src;
        float4 v1 = *(const float4*)(src + 4);
        us8 o = { f2b(v0.x), f2b(v0.y), f2b(v0.z), f2b(v0.w),
                  f2b(v1.x), f2b(v1.y), f2b(v1.z), f2b(v1.w) };
        size_t off = (size_t)(n >> 4) * 4096 + (size_t)(k8 >> 2) * 512
                   + (size_t)(k8 & 3) * 128 + (size_t)(n & 15) * 8;
        *(us8*)(B2f + off) = o;
    } else {
        int t = (b - 3189) * 256 + threadIdx.x;
        if (t < (NN + 3) / 4) *(int4*)(cnt + t * 4) = make_int4(0, 0, 0, 0);
    }
}

// ---- single-pass CSR fill, dst-range partitioned; ei loads are non-temporal
//      so the edge stream doesn't evict cnt/csr lines from the XCD L2 ----
__global__ __launch_bounds__(256) void k_fill(const int* __restrict__ ei,
                                              int* __restrict__ cnt,
                                              unsigned short* __restrict__ csr) {
    const int r = blockIdx.x & 7;
    const int c = blockIdx.x >> 3;
    const int lo = r * RSZ, hi = lo + RSZ;
    const int base = c * EPB + threadIdx.x;
#pragma unroll
    for (int i = 0; i < EPB / 256; ++i) {
        int e = base + i * 256;
        if (e < NE) {
            int dst = __builtin_nontemporal_load(ei + NE + e);
            if (dst >= lo && dst < hi) {
                int srcv = __builtin_nontemporal_load(ei + e);
                int old = atomicAdd(&cnt[dst], 1);
                if (old < CAP) csr[dst * CAP + old] = (unsigned short)srcv;
            }
        }
    }
}

// ---- gather mean: reads x rows from A1f x-half (frag layout, us8-contiguous
//      per lane), writes frag A1f mean-half (k=0..127) ----
__global__ __launch_bounds__(256) void k_gather_mean(
    const int* __restrict__ cnt, const unsigned short* __restrict__ csr,
    unsigned short* __restrict__ A1f) {
    const int node = blockIdx.x * 4 + (threadIdx.x >> 6);
    const int lane = threadIdx.x & 63;
    const int sub = lane >> 4;
    const int cl = lane & 15;
    const int cn = cnt[node];
    const int m = (cn < CAP) ? cn : CAP;
    const unsigned short* cb = csr + node * CAP;
    float acc[8] = {};
    // per-lane constant offset within a row-block for x chunk (k = 128 + cl*8)
    const int xoff = (4 + (cl >> 2)) * 512 + (cl & 3) * 128;
    int i = sub;
    for (; i + 4 < m; i += 8) {
        int s0 = cb[i], s1 = cb[i + 4];
        us8 v0 = *(const us8*)(A1f + (size_t)(s0 >> 4) * 4096 + xoff + (s0 & 15) * 8);
        us8 v1 = *(const us8*)(A1f + (size_t)(s1 >> 4) * 4096 + xoff + (s1 & 15) * 8);
#pragma unroll
        for (int j = 0; j < 8; ++j) acc[j] += b2f(v0[j]) + b2f(v1[j]);
    }
    if (i < m) {
        int s0 = cb[i];
        us8 v0 = *(const us8*)(A1f + (size_t)(s0 >> 4) * 4096 + xoff + (s0 & 15) * 8);
#pragma unroll
        for (int j = 0; j < 8; ++j) acc[j] += b2f(v0[j]);
    }
#pragma unroll
    for (int j = 0; j < 8; ++j) {
        acc[j] += __shfl_xor(acc[j], 16, 64);
        acc[j] += __shfl_xor(acc[j], 32, 64);
    }
    if (sub == 0) {
        float inv = 1.0f / fmaxf((float)cn, 1.0f);
        us8 o;
#pragma unroll
        for (int j = 0; j < 8; ++j) o[j] = f2b(acc[j] * inv);
        size_t off = (size_t)(node >> 4) * 4096 + (size_t)(cl >> 2) * 512
                   + (size_t)(cl & 3) * 128 + (size_t)(node & 15) * 8;
        *(us8*)(A1f + off) = o;
    }
}

// ---- FUSED dual-layer MFMA GEMM (as R10) ----
__global__ __launch_bounds__(256) void k_mgemm_fused(
    const unsigned short* __restrict__ A, const unsigned short* __restrict__ B1,
    const float* __restrict__ b1, const unsigned short* __restrict__ B2,
    const float* __restrict__ b2, unsigned short* __restrict__ HP,
    float* __restrict__ OUT) {
    __shared__ unsigned short Hsl[16384];   // 32 KB: A-tile, then h-tile
    const int tid = threadIdx.x;
    const int lane = tid & 63;
    const int w = tid >> 6;
    const int col = lane & 15, quad = lane >> 4;
    const int m0 = blockIdx.x * 64;

    {
        const us8* src = (const us8*)(A + (size_t)(m0 >> 4) * 4096);
        us8* dst = (us8*)Hsl;
#pragma unroll
        for (int i = 0; i < 8; ++i) dst[tid + i * 256] = src[tid + i * 256];
    }
    __syncthreads();

    f32x4 acc[4][4];
#pragma unroll
    for (int i = 0; i < 4; ++i)
#pragma unroll
        for (int j = 0; j < 4; ++j) acc[i][j] = (f32x4){0.f, 0.f, 0.f, 0.f};
#pragma unroll
    for (int kc = 0; kc < 8; ++kc) {
        bfrag a[4], b[4];
#pragma unroll
        for (int mt = 0; mt < 4; ++mt)
            a[mt] = *(const bfrag*)(Hsl + mt * 4096 + kc * 512 + quad * 128 + col * 8);
#pragma unroll
        for (int nt = 0; nt < 4; ++nt)
            b[nt] = *(const bfrag*)(B1 + (size_t)(w * 4 + nt) * 4096 + kc * 512 + quad * 128 + col * 8);
#pragma unroll
        for (int mt = 0; mt < 4; ++mt)
#pragma unroll
            for (int nt = 0; nt < 4; ++nt)
                acc[mt][nt] = __builtin_amdgcn_mfma_f32_16x16x32_bf16(a[mt], b[nt], acc[mt][nt], 0, 0, 0);
    }
    __syncthreads();

#pragma unroll
    for (int nt = 0; nt < 4; ++nt) {
        int n = w * 64 + nt * 16 + col;
        float bb = b1[n];
        int noff = (n >> 5) * 512 + ((n >> 3) & 3) * 128 + (n & 7);
#pragma unroll
        for (int mt = 0; mt < 4; ++mt) {
#pragma unroll
            for (int r = 0; r < 4; ++r) {
                int ml = quad * 4 + r;
                Hsl[mt * 4096 + noff + ml * 8] = f2b(fmaxf(acc[mt][nt][r] + bb, 0.f));
            }
        }
    }
    __syncthreads();

#pragma unroll
    for (int i = 0; i < 4; ++i)
#pragma unroll
        for (int j = 0; j < 4; ++j) acc[i][j] = (f32x4){0.f, 0.f, 0.f, 0.f};
#pragma unroll
    for (int kc = 0; kc < 8; ++kc) {
        bfrag a[4], b[4];
#pragma unroll
        for (int mt = 0; mt < 4; ++mt)
            a[mt] = *(const bfrag*)(Hsl + mt * 4096 + kc * 512 + quad * 128 + col * 8);
#pragma unroll
        for (int nt = 0; nt < 4; ++nt)
            b[nt] = *(const bfrag*)(B2 + (size_t)(w * 4 + nt) * 4096 + kc * 512 + quad * 128 + col * 8);
#pragma unroll
        for (int mt = 0; mt < 4; ++mt)
#pragma unroll
            for (int nt = 0; nt < 4; ++nt)
                acc[mt][nt] = __builtin_amdgcn_mfma_f32_16x16x32_bf16(a[mt], b[nt], acc[mt][nt], 0, 0, 0);
    }

    if (w < 2) {
#pragma unroll
        for (int mt = 0; mt < 4; ++mt)
#pragma unroll
            for (int nt = 0; nt < 4; ++nt) {
                int n = w * 64 + nt * 16 + col;
#pragma unroll
                for (int r = 0; r < 4; ++r) {
                    int m = m0 + mt * 16 + quad * 4 + r;
                    if (m < NN) HP[(size_t)m * OUTC + n] = f2b(acc[mt][nt][r]);
                }
            }
    } else {
#pragma unroll
        for (int mt = 0; mt < 4; ++mt)
#pragma unroll
            for (int nt = 0; nt < 4; ++nt) {
                int n = (w - 2) * 64 + nt * 16 + col;
                float bb = b2[n];
#pragma unroll
                for (int r = 0; r < 4; ++r) {
                    int m = m0 + mt * 16 + quad * 4 + r;
                    if (m < NN) OUT[(size_t)m * OUTC + n] = acc[mt][nt][r] + bb;
                }
            }
    }
}

// ---- final: out += mean(hp over neighbors), hp plain bf16 ----
__global__ __launch_bounds__(256) void k_gather_add(
    const int* __restrict__ cnt, const unsigned short* __restrict__ csr,
    const unsigned short* __restrict__ hp, float* __restrict__ out) {
    const int node = blockIdx.x * 4 + (threadIdx.x >> 6);
    const int lane = threadIdx.x & 63;
    const int sub = lane >> 4;
    const int cl = lane & 15;
    const int cn = cnt[node];
    const int m = (cn < CAP) ? cn : CAP;
    const unsigned short* cb = csr + node * CAP;
    float acc[8] = {};
    const unsigned short* hb = hp + cl * 8;
    int i = sub;
    for (; i + 4 < m; i += 8) {
        int s0 = cb[i], s1 = cb[i + 4];
        us8 v0 = *(const us8*)(hb + (size_t)s0 * OUTC);
        us8 v1 = *(const us8*)(hb + (size_t)s1 * OUTC);
#pragma unroll
        for (int j = 0; j < 8; ++j) acc[j] += b2f(v0[j]) + b2f(v1[j]);
    }
    if (i < m) {
        int s0 = cb[i];
        us8 v0 = *(const us8*)(hb + (size_t)s0 * OUTC);
#pragma unroll
        for (int j = 0; j < 8; ++j) acc[j] += b2f(v0[j]);
    }
#pragma unroll
    for (int j = 0; j < 8; ++j) {
        acc[j] += __shfl_xor(acc[j], 16, 64);
        acc[j] += __shfl_xor(acc[j], 32, 64);
    }
    if (sub == 0) {
        float inv = 1.0f / fmaxf((float)cn, 1.0f);
        float* p = out + (size_t)node * OUTC + cl * 8;
        float4 c0v = *(float4*)p;
        float4 c1v = *(float4*)(p + 4);
        c0v.x += acc[0] * inv; c0v.y += acc[1] * inv;
        c0v.z += acc[2] * inv; c0v.w += acc[3] * inv;
        c1v.x += acc[4] * inv; c1v.y += acc[5] * inv;
        c1v.z += acc[6] * inv; c1v.w += acc[7] * inv;
        *(float4*)p = c0v;
        *(float4*)(p + 4) = c1v;
    }
}

extern "C" void kernel_launch(void* const* d_in, const int* in_sizes, int n_in,
                              void* d_out, int out_size, void* d_ws, size_t ws_size,
                              hipStream_t stream) {
    const float* x   = (const float*)d_in[0];
    const int*   ei  = (const int*)d_in[1];
    const float* W1l = (const float*)d_in[2];
    const float* b1  = (const float*)d_in[3];
    const float* W1r = (const float*)d_in[4];
    const float* W2l = (const float*)d_in[5];
    const float* b2  = (const float*)d_in[6];
    const float* W2r = (const float*)d_in[7];
    float* out = (float*)d_out;

    // layout: cnt[NN] int | csr[NN*CAP] u16 | A1f | hp | B1f | B2f
    int* cnt = (int*)d_ws;
    unsigned short* csr = (unsigned short*)(cnt + ((NN + 63) & ~63));
    unsigned short* A1f = csr + (size_t)NN * CAP;                 // [MP][256] frag
    unsigned short* hp  = A1f + (size_t)MP * 256;                 // [NN][128] plain
    unsigned short* B1f = hp + (size_t)NN * 128;                  // [256][256] frag
    unsigned short* B2f = B1f + 256 * 256;                        // [256][256] frag

    k_prep<<<3238, 256, 0, stream>>>(x, W1l, W1r, W2l, W2r, A1f, B1f, B2f, cnt);
    k_fill<<<NCH * 8, 256, 0, stream>>>(ei, cnt, csr);
    k_gather_mean<<<NN / 4, 256, 0, stream>>>(cnt, csr, A1f);

    k_mgemm_fused<<<MP / 64, 256, 0, stream>>>(A1f, B1f, b1, B2f, b2, hp, out);

    k_gather_add<<<NN / 4, 256, 0, stream>>>(cnt, csr, hp, out);
}

// Round 12
// 229.235 us; speedup vs baseline: 1.5560x; 1.5560x over previous
//
#include <hip/hip_runtime.h>

#define NN   50000
#define INC  128
#define HIDC 256
#define OUTC 128
#define NE   800000
#define MP   50048   // NN padded to 128
#define CAP  64      // CSR capacity per node (P(deg>64) ~ 1e-22)

#define EPB 4096                            // edges per chunk-block
#define NCH ((NE + EPB - 1) / EPB)          // 196 chunks
#define RSZ 6250                            // nodes per dst-range (50000/8)

typedef short bfrag __attribute__((ext_vector_type(8)));   // 8 bf16 = 4 VGPRs
typedef float f32x4 __attribute__((ext_vector_type(4)));
typedef unsigned short us8 __attribute__((ext_vector_type(8)));

__device__ inline unsigned short f2b(float f) {
    union { float f; unsigned u; } v; v.f = f;
    unsigned u = v.u;
    return (unsigned short)((u + 0x7fffu + ((u >> 16) & 1u)) >> 16);
}
__device__ inline float b2f(unsigned short s) {
    union { unsigned u; float f; } v; v.u = ((unsigned)s) << 16;
    return v.f;
}

// ---- fused prep: zero cnt | cast x (plain xb16 + frag A1f x-half) | W1 | W2 ----
__global__ __launch_bounds__(256) void k_prep(
    const float* __restrict__ x, const float* __restrict__ W1l,
    const float* __restrict__ W1r, const float* __restrict__ W2l,
    const float* __restrict__ W2r, unsigned short* __restrict__ xb16,
    unsigned short* __restrict__ A1f, unsigned short* __restrict__ B1f,
    unsigned short* __restrict__ B2f, int* __restrict__ cnt) {
    const int b = blockIdx.x;
    if (b < 3125) {
        int t = b * 256 + threadIdx.x;          // < NN*16 = 800000
        int i = t >> 4;
        int c8 = t & 15;
        const float* src = x + (size_t)i * INC + c8 * 8;
        float4 v0 = *(const float4*)src;
        float4 v1 = *(const float4*)(src + 4);
        us8 o = { f2b(v0.x), f2b(v0.y), f2b(v0.z), f2b(v0.w),
                  f2b(v1.x), f2b(v1.y), f2b(v1.z), f2b(v1.w) };
        *(us8*)(xb16 + (size_t)i * INC + c8 * 8) = o;
        size_t off = (size_t)(i >> 4) * 4096 + (size_t)(4 + (c8 >> 2)) * 512
                   + (size_t)(c8 & 3) * 128 + (size_t)(i & 15) * 8;
        *(us8*)(A1f + off) = o;
    } else if (b < 3157) {
        int t = (b - 3125) * 256 + threadIdx.x; // < 8192
        int n = t >> 5;
        int k8 = t & 31;
        int k = k8 * 8;
        const float* src = (k < 128) ? (W1l + (size_t)n * INC + k)
                                     : (W1r + (size_t)n * INC + (k - 128));
        float4 v0 = *(const float4*)src;
        float4 v1 = *(const float4*)(src + 4);
        us8 o = { f2b(v0.x), f2b(v0.y), f2b(v0.z), f2b(v0.w),
                  f2b(v1.x), f2b(v1.y), f2b(v1.z), f2b(v1.w) };
        size_t off = (size_t)(n >> 4) * 4096 + (size_t)(k8 >> 2) * 512
                   + (size_t)(k8 & 3) * 128 + (size_t)(n & 15) * 8;
        *(us8*)(B1f + off) = o;
    } else if (b < 3189) {
        int t = (b - 3157) * 256 + threadIdx.x; // < 8192
        int n = t >> 5;
        int k8 = t & 31;
        const float* src = (n < 128) ? (W2l + (size_t)n * HIDC + k8 * 8)
                                     : (W2r + (size_t)(n - 128) * HIDC + k8 * 8);
        float4 v0 = *(const float4*)src;
        float4 v1 = *(const float4*)(src + 4);
        us8 o = { f2b(v0.x), f2b(v0.y), f2b(v0.z), f2b(v0.w),
                  f2b(v1.x), f2b(v1.y), f2b(v1.z), f2b(v1.w) };
        size_t off = (size_t)(n >> 4) * 4096 + (size_t)(k8 >> 2) * 512
                   + (size_t)(k8 & 3) * 128 + (size_t)(n & 15) * 8;
        *(us8*)(B2f + off) = o;
    } else {
        int t = (b - 3189) * 256 + threadIdx.x;
        if (t < (NN + 3) / 4) *(int4*)(cnt + t * 4) = make_int4(0, 0, 0, 0);
    }
}

// ---- single-pass CSR fill, dst-range partitioned; ei loads non-temporal ----
__global__ __launch_bounds__(256) void k_fill(const int* __restrict__ ei,
                                              int* __restrict__ cnt,
                                              unsigned short* __restrict__ csr) {
    const int r = blockIdx.x & 7;
    const int c = blockIdx.x >> 3;
    const int lo = r * RSZ, hi = lo + RSZ;
    const int base = c * EPB + threadIdx.x;
#pragma unroll
    for (int i = 0; i < EPB / 256; ++i) {
        int e = base + i * 256;
        if (e < NE) {
            int dst = __builtin_nontemporal_load(ei + NE + e);
            if (dst >= lo && dst < hi) {
                int srcv = __builtin_nontemporal_load(ei + e);
                int old = atomicAdd(&cnt[dst], 1);
                if (old < CAP) csr[dst * CAP + old] = (unsigned short)srcv;
            }
        }
    }
}

// ---- gather mean: reads plain xb16 rows, writes frag A1f mean-half ----
__global__ __launch_bounds__(256) void k_gather_mean(
    const int* __restrict__ cnt, const unsigned short* __restrict__ csr,
    const unsigned short* __restrict__ xb16, unsigned short* __restrict__ A1f) {
    const int node = blockIdx.x * 4 + (threadIdx.x >> 6);
    const int lane = threadIdx.x & 63;
    const int sub = lane >> 4;
    const int cl = lane & 15;
    const int cn = cnt[node];
    const int m = (cn < CAP) ? cn : CAP;
    const unsigned short* cb = csr + node * CAP;
    float acc[8] = {};
    const unsigned short* xb = xb16 + cl * 8;
    int i = sub;
    for (; i + 4 < m; i += 8) {
        int s0 = cb[i], s1 = cb[i + 4];
        us8 v0 = *(const us8*)(xb + (size_t)s0 * INC);
        us8 v1 = *(const us8*)(xb + (size_t)s1 * INC);
#pragma unroll
        for (int j = 0; j < 8; ++j) acc[j] += b2f(v0[j]) + b2f(v1[j]);
    }
    if (i < m) {
        int s0 = cb[i];
        us8 v0 = *(const us8*)(xb + (size_t)s0 * INC);
#pragma unroll
        for (int j = 0; j < 8; ++j) acc[j] += b2f(v0[j]);
    }
#pragma unroll
    for (int j = 0; j < 8; ++j) {
        acc[j] += __shfl_xor(acc[j], 16, 64);
        acc[j] += __shfl_xor(acc[j], 32, 64);
    }
    if (sub == 0) {
        float inv = 1.0f / fmaxf((float)cn, 1.0f);
        us8 o;
#pragma unroll
        for (int j = 0; j < 8; ++j) o[j] = f2b(acc[j] * inv);
        size_t off = (size_t)(node >> 4) * 4096 + (size_t)(cl >> 2) * 512
                   + (size_t)(cl & 3) * 128 + (size_t)(node & 15) * 8;
        *(us8*)(A1f + off) = o;
    }
}

// ---- FUSED dual-layer MFMA GEMM ----
__global__ __launch_bounds__(256) void k_mgemm_fused(
    const unsigned short* __restrict__ A, const unsigned short* __restrict__ B1,
    const float* __restrict__ b1, const unsigned short* __restrict__ B2,
    const float* __restrict__ b2, unsigned short* __restrict__ HP,
    float* __restrict__ OUT) {
    __shared__ unsigned short Hsl[16384];   // 32 KB: A-tile, then h-tile
    const int tid = threadIdx.x;
    const int lane = tid & 63;
    const int w = tid >> 6;
    const int col = lane & 15, quad = lane >> 4;
    const int m0 = blockIdx.x * 64;

    {
        const us8* src = (const us8*)(A + (size_t)(m0 >> 4) * 4096);
        us8* dst = (us8*)Hsl;
#pragma unroll
        for (int i = 0; i < 8; ++i) dst[tid + i * 256] = src[tid + i * 256];
    }
    __syncthreads();

    f32x4 acc[4][4];
#pragma unroll
    for (int i = 0; i < 4; ++i)
#pragma unroll
        for (int j = 0; j < 4; ++j) acc[i][j] = (f32x4){0.f, 0.f, 0.f, 0.f};
#pragma unroll
    for (int kc = 0; kc < 8; ++kc) {
        bfrag a[4], b[4];
#pragma unroll
        for (int mt = 0; mt < 4; ++mt)
            a[mt] = *(const bfrag*)(Hsl + mt * 4096 + kc * 512 + quad * 128 + col * 8);
#pragma unroll
        for (int nt = 0; nt < 4; ++nt)
            b[nt] = *(const bfrag*)(B1 + (size_t)(w * 4 + nt) * 4096 + kc * 512 + quad * 128 + col * 8);
#pragma unroll
        for (int mt = 0; mt < 4; ++mt)
#pragma unroll
            for (int nt = 0; nt < 4; ++nt)
                acc[mt][nt] = __builtin_amdgcn_mfma_f32_16x16x32_bf16(a[mt], b[nt], acc[mt][nt], 0, 0, 0);
    }
    __syncthreads();

#pragma unroll
    for (int nt = 0; nt < 4; ++nt) {
        int n = w * 64 + nt * 16 + col;
        float bb = b1[n];
        int noff = (n >> 5) * 512 + ((n >> 3) & 3) * 128 + (n & 7);
#pragma unroll
        for (int mt = 0; mt < 4; ++mt) {
#pragma unroll
            for (int r = 0; r < 4; ++r) {
                int ml = quad * 4 + r;
                Hsl[mt * 4096 + noff + ml * 8] = f2b(fmaxf(acc[mt][nt][r] + bb, 0.f));
            }
        }
    }
    __syncthreads();

#pragma unroll
    for (int i = 0; i < 4; ++i)
#pragma unroll
        for (int j = 0; j < 4; ++j) acc[i][j] = (f32x4){0.f, 0.f, 0.f, 0.f};
#pragma unroll
    for (int kc = 0; kc < 8; ++kc) {
        bfrag a[4], b[4];
#pragma unroll
        for (int mt = 0; mt < 4; ++mt)
            a[mt] = *(const bfrag*)(Hsl + mt * 4096 + kc * 512 + quad * 128 + col * 8);
#pragma unroll
        for (int nt = 0; nt < 4; ++nt)
            b[nt] = *(const bfrag*)(B2 + (size_t)(w * 4 + nt) * 4096 + kc * 512 + quad * 128 + col * 8);
#pragma unroll
        for (int mt = 0; mt < 4; ++mt)
#pragma unroll
            for (int nt = 0; nt < 4; ++nt)
                acc[mt][nt] = __builtin_amdgcn_mfma_f32_16x16x32_bf16(a[mt], b[nt], acc[mt][nt], 0, 0, 0);
    }

    if (w < 2) {
#pragma unroll
        for (int mt = 0; mt < 4; ++mt)
#pragma unroll
            for (int nt = 0; nt < 4; ++nt) {
                int n = w * 64 + nt * 16 + col;
#pragma unroll
                for (int r = 0; r < 4; ++r) {
                    int m = m0 + mt * 16 + quad * 4 + r;
                    if (m < NN) HP[(size_t)m * OUTC + n] = f2b(acc[mt][nt][r]);
                }
            }
    } else {
#pragma unroll
        for (int mt = 0; mt < 4; ++mt)
#pragma unroll
            for (int nt = 0; nt < 4; ++nt) {
                int n = (w - 2) * 64 + nt * 16 + col;
                float bb = b2[n];
#pragma unroll
                for (int r = 0; r < 4; ++r) {
                    int m = m0 + mt * 16 + quad * 4 + r;
                    if (m < NN) OUT[(size_t)m * OUTC + n] = acc[mt][nt][r] + bb;
                }
            }
    }
}

// ---- final: out += mean(hp over neighbors), hp plain bf16 ----
__global__ __launch_bounds__(256) void k_gather_add(
    const int* __restrict__ cnt, const unsigned short* __restrict__ csr,
    const unsigned short* __restrict__ hp, float* __restrict__ out) {
    const int node = blockIdx.x * 4 + (threadIdx.x >> 6);
    const int lane = threadIdx.x & 63;
    const int sub = lane >> 4;
    const int cl = lane & 15;
    const int cn = cnt[node];
    const int m = (cn < CAP) ? cn : CAP;
    const unsigned short* cb = csr + node * CAP;
    float acc[8] = {};
    const unsigned short* hb = hp + cl * 8;
    int i = sub;
    for (; i + 4 < m; i += 8) {
        int s0 = cb[i], s1 = cb[i + 4];
        us8 v0 = *(const us8*)(hb + (size_t)s0 * OUTC);
        us8 v1 = *(const us8*)(hb + (size_t)s1 * OUTC);
#pragma unroll
        for (int j = 0; j < 8; ++j) acc[j] += b2f(v0[j]) + b2f(v1[j]);
    }
    if (i < m) {
        int s0 = cb[i];
        us8 v0 = *(const us8*)(hb + (size_t)s0 * OUTC);
#pragma unroll
        for (int j = 0; j < 8; ++j) acc[j] += b2f(v0[j]);
    }
#pragma unroll
    for (int j = 0; j < 8; ++j) {
        acc[j] += __shfl_xor(acc[j], 16, 64);
        acc[j] += __shfl_xor(acc[j], 32, 64);
    }
    if (sub == 0) {
        float inv = 1.0f / fmaxf((float)cn, 1.0f);
        float* p = out + (size_t)node * OUTC + cl * 8;
        float4 c0v = *(float4*)p;
        float4 c1v = *(float4*)(p + 4);
        c0v.x += acc[0] * inv; c0v.y += acc[1] * inv;
        c0v.z += acc[2] * inv; c0v.w += acc[3] * inv;
        c1v.x += acc[4] * inv; c1v.y += acc[5] * inv;
        c1v.z += acc[6] * inv; c1v.w += acc[7] * inv;
        *(float4*)p = c0v;
        *(float4*)(p + 4) = c1v;
    }
}

extern "C" void kernel_launch(void* const* d_in, const int* in_sizes, int n_in,
                              void* d_out, int out_size, void* d_ws, size_t ws_size,
                              hipStream_t stream) {
    const float* x   = (const float*)d_in[0];
    const int*   ei  = (const int*)d_in[1];
    const float* W1l = (const float*)d_in[2];
    const float* b1  = (const float*)d_in[3];
    const float* W1r = (const float*)d_in[4];
    const float* W2l = (const float*)d_in[5];
    const float* b2  = (const float*)d_in[6];
    const float* W2r = (const float*)d_in[7];
    float* out = (float*)d_out;

    // layout: cnt[NN] int | csr[NN*CAP] u16 | A1f | xb16 | hp | B1f | B2f
    int* cnt = (int*)d_ws;
    unsigned short* csr = (unsigned short*)(cnt + ((NN + 63) & ~63));
    unsigned short* A1f  = csr + (size_t)NN * CAP;                // [MP][256] frag
    unsigned short* xb16 = A1f + (size_t)MP * 256;                // [NN][128] plain
    unsigned short* hp   = xb16 + (size_t)NN * 128;               // [NN][128] plain
    unsigned short* B1f  = hp + (size_t)NN * 128;                 // [256][256] frag
    unsigned short* B2f  = B1f + 256 * 256;                       // [256][256] frag

    k_prep<<<3238, 256, 0, stream>>>(x, W1l, W1r, W2l, W2r, xb16, A1f, B1f, B2f, cnt);
    k_fill<<<NCH * 8, 256, 0, stream>>>(ei, cnt, csr);
    k_gather_mean<<<NN / 4, 256, 0, stream>>>(cnt, csr, xb16, A1f);

    k_mgemm_fused<<<MP / 64, 256, 0, stream>>>(A1f, B1f, b1, B2f, b2, hp, out);

    k_gather_add<<<NN / 4, 256, 0, stream>>>(cnt, csr, hp, out);
}